// Round 6
// baseline (720.543 us; speedup 1.0000x reference)
//
#include <hip/hip_runtime.h>
#include <hip/hip_bf16.h>
#include <math.h>

typedef __attribute__((ext_vector_type(8))) short bf16x8;
typedef __attribute__((ext_vector_type(4))) float f32x4;
typedef __attribute__((ext_vector_type(16))) float f32x16;
typedef __attribute__((ext_vector_type(4))) unsigned int u32x4;

#if __has_builtin(__builtin_amdgcn_exp2f)
#define EXP2(x) __builtin_amdgcn_exp2f(x)
#else
#define EXP2(x) __expf((x) * 0.6931471805599453f)
#endif

__device__ __forceinline__ ushort f2bf(float f) {
  unsigned u = __float_as_uint(f);
  u = u + 0x7FFFu + ((u >> 16) & 1u);
  return (ushort)(u >> 16);
}
__device__ __forceinline__ float bf2f(ushort h) {
  return __uint_as_float(((unsigned)h) << 16);
}
// single-instruction packed f32->bf16 pair (RNE, same as manual round)
__device__ __forceinline__ unsigned cvtpk(float a, float b) {
  unsigned r;
  asm("v_cvt_pk_bf16_f32 %0, %1, %2" : "=v"(r) : "v"(a), "v"(b));
  return r;
}
__device__ __forceinline__ void gload_lds16(const ushort* g, ushort* l) {
  __builtin_amdgcn_global_load_lds((const __attribute__((address_space(1))) void*)g,
                                   (__attribute__((address_space(3))) void*)l, 16, 0, 0);
}

// ---------------------------------------------------------------- prep: casts + packing + rope table
__global__ __launch_bounds__(256) void prep_kernel(
    const float* __restrict__ hs, const float* __restrict__ qw,
    const float* __restrict__ kw, const float* __restrict__ vw,
    const float* __restrict__ ow, const float* __restrict__ qb,
    const float* __restrict__ kb, const float* __restrict__ vb,
    ushort* __restrict__ hs_b, ushort* __restrict__ qkvw_b,
    ushort* __restrict__ ow_b, float* __restrict__ qkvb,
    float2* __restrict__ rope_tab)
{
  const int idx = blockIdx.x * 256 + threadIdx.x;
  const int stride = gridDim.x * 256;
  const float4* hs4 = (const float4*)hs;
  const float4* qw4 = (const float4*)qw;
  const float4* kw4 = (const float4*)kw;
  const float4* vw4 = (const float4*)vw;
  const float4* ow4 = (const float4*)ow;
  ushort4* hsb4 = (ushort4*)hs_b;
  ushort4* qkvwb4 = (ushort4*)qkvw_b;
  ushort4* owb4 = (ushort4*)ow_b;

  for (int i = idx; i < 2097152; i += stride) {
    float4 v = hs4[i];
    ushort4 o; o.x=f2bf(v.x); o.y=f2bf(v.y); o.z=f2bf(v.z); o.w=f2bf(v.w);
    hsb4[i] = o;
  }
  for (int i = idx; i < 1048576; i += stride) {
    float4 v = qw4[i];
    ushort4 o; o.x=f2bf(v.x); o.y=f2bf(v.y); o.z=f2bf(v.z); o.w=f2bf(v.w);
    qkvwb4[i] = o;
  }
  for (int i = idx; i < 262144; i += stride) {
    float4 v = kw4[i];
    ushort4 o; o.x=f2bf(v.x); o.y=f2bf(v.y); o.z=f2bf(v.z); o.w=f2bf(v.w);
    qkvwb4[1048576 + i] = o;
  }
  for (int i = idx; i < 262144; i += stride) {
    float4 v = vw4[i];
    ushort4 o; o.x=f2bf(v.x); o.y=f2bf(v.y); o.z=f2bf(v.z); o.w=f2bf(v.w);
    qkvwb4[1310720 + i] = o;
  }
  for (int i = idx; i < 1048576; i += stride) {
    float4 v = ow4[i];
    ushort4 o; o.x=f2bf(v.x); o.y=f2bf(v.y); o.z=f2bf(v.z); o.w=f2bf(v.w);
    owb4[i] = o;
  }
  for (int i = idx; i < 3072; i += stride)
    qkvb[i] = (i < 2048) ? qb[i] : (i < 2560 ? kb[i - 2048] : vb[i - 2560]);
  // rope cos/sin table: [pos 0..2047][pair 0..63]
  for (int i = idx; i < 131072; i += stride) {
    int pos = i >> 6, d = i & 63;
    float inv = __expf((float)d * -0.14391156831212787f);
    float ang = (float)pos * inv;
    rope_tab[i] = make_float2(cosf(ang), sinf(ang));
  }
}

// ---------------------------------------------------------------- GEMM1: QKV projection + fused RoPE
// R4-proven: acc[4][4] 64x64/wave, 8 ds_read_b128 + 16 MFMA per K-step, DMA dbuf.
// Rope in-lane via paired frag-cols {0,1,4,5}/{2,3,6,7} (closed under +64 cols).
__global__ __launch_bounds__(256) void gemm_qkv(
    const ushort* __restrict__ A, const ushort* __restrict__ Bw,
    const float* __restrict__ bias, ushort* __restrict__ qkbuf,
    ushort* __restrict__ vt, const float2* __restrict__ tab)
{
  __shared__ ushort sm[2][8192];  // [buf][A 0..4095 | B 4096..8191]
  const int t = threadIdx.x;
  const int wv = t >> 6;
  const int lane = t & 63;
  const int qd = lane >> 4, ln = lane & 15;
  const long row0 = (long)blockIdx.x * 128;
  const long col0 = (long)blockIdx.y * 128;
  const int wm = (wv >> 1) * 64;
  const int cbase = (wv & 1) * 2;  // frag-col set: {0,1,4,5} or {2,3,6,7}

  f32x4 acc[4][4];
#pragma unroll
  for (int i = 0; i < 4; i++)
#pragma unroll
    for (int j = 0; j < 4; j++) acc[i][j] = (f32x4){0.f, 0.f, 0.f, 0.f};

  const ushort* gA = A + (row0 + (t >> 2)) * 2048l + (t & 3) * 8;
  const ushort* gB = Bw + (col0 + (t >> 2)) * 2048l + (t & 3) * 8;
  const int lo = wv * 512;
  const long K64 = 64l * 2048;

  gload_lds16(gA,       &sm[0][lo]);
  gload_lds16(gA + K64, &sm[0][lo + 2048]);
  gload_lds16(gB,       &sm[0][4096 + lo]);
  gload_lds16(gB + K64, &sm[0][4096 + lo + 2048]);

  for (int kt = 0; kt < 2048; kt += 32) {
    const int cb = (kt >> 5) & 1;
    __syncthreads();
    if (kt < 2016) {
      ushort* nb = &sm[cb ^ 1][0];
      gload_lds16(gA + kt + 32,       nb + lo);
      gload_lds16(gA + kt + 32 + K64, nb + lo + 2048);
      gload_lds16(gB + kt + 32,       nb + 4096 + lo);
      gload_lds16(gB + kt + 32 + K64, nb + 4096 + lo + 2048);
    }
    const ushort* Asb = &sm[cb][0];
    const ushort* Bsb = &sm[cb][4096];
    bf16x8 af[4], bf[4];
#pragma unroll
    for (int mi = 0; mi < 4; mi++)
      af[mi] = *(const bf16x8*)&Asb[(wm + mi * 16 + ln) * 32 + qd * 8];
#pragma unroll
    for (int ni = 0; ni < 4; ni++) {
      const int p = cbase + (ni & 1) + (ni >> 1) * 4;
      bf[ni] = *(const bf16x8*)&Bsb[(p * 16 + ln) * 32 + qd * 8];
    }
#pragma unroll
    for (int mi = 0; mi < 4; mi++)
#pragma unroll
      for (int ni = 0; ni < 4; ni++)
        acc[mi][ni] = __builtin_amdgcn_mfma_f32_16x16x32_bf16(af[mi], bf[ni], acc[mi][ni], 0, 0, 0);
  }

  int pcol[4];
  float bv[4];
#pragma unroll
  for (int ni = 0; ni < 4; ni++) {
    pcol[ni] = cbase + (ni & 1) + (ni >> 1) * 4;
    bv[ni] = bias[col0 + pcol[ni] * 16 + ln];
  }

  if (col0 >= 2560) {
#pragma unroll
    for (int mi = 0; mi < 4; mi++)
#pragma unroll
      for (int ni = 0; ni < 4; ni++)
#pragma unroll
        for (int r = 0; r < 4; r++) {
          long row = row0 + wm + mi * 16 + qd * 4 + r;
          long col = col0 + pcol[ni] * 16 + ln - 2560;
          vt[col * 4096 + row] = f2bf(acc[mi][ni][r] + bv[ni]);
        }
  } else {
    const float sc = (col0 < 2048) ? 0.12751744399764505f : 1.0f;  // log2(e)/sqrt(128)
#pragma unroll
    for (int mi = 0; mi < 4; mi++)
#pragma unroll
      for (int ni = 0; ni < 2; ni++) {
        const int d = (cbase + ni) * 16 + ln;   // in [0,64)
#pragma unroll
        for (int r = 0; r < 4; r++) {
          long row = row0 + wm + mi * 16 + qd * 4 + r;
          int pos = (int)(row & 2047);
          float2 cs = tab[pos * 64 + d];
          float c = cs.x * sc, s = cs.y * sc;
          float v0 = acc[mi][ni][r]     + bv[ni];
          float v1 = acc[mi][ni + 2][r] + bv[ni + 2];
          ushort* p = qkbuf + row * 2560 + col0 + d;
          p[0]  = f2bf(v0 * c - v1 * s);
          p[64] = f2bf(v1 * c + v0 * s);
        }
      }
  }
}

// ---------------------------------------------------------------- GEMM2: C = A(MxK) * Bw(NxK)^T + bias (f32 out)
__global__ __launch_bounds__(256) void gemm_bt(
    const ushort* __restrict__ A, const ushort* __restrict__ Bw,
    const float* __restrict__ bias, float* __restrict__ Cout,
    int K, int ldc)
{
  __shared__ ushort sm[2][8192];
  const int t = threadIdx.x;
  const int wv = t >> 6;
  const int lane = t & 63;
  const int qd = lane >> 4, ln = lane & 15;
  const long row0 = (long)blockIdx.x * 128;
  const long col0 = (long)blockIdx.y * 128;
  const int wm = (wv >> 1) * 64, wn = (wv & 1) * 64;

  f32x4 acc[4][4];
#pragma unroll
  for (int i = 0; i < 4; i++)
#pragma unroll
    for (int j = 0; j < 4; j++) acc[i][j] = (f32x4){0.f, 0.f, 0.f, 0.f};

  const ushort* gA = A + (row0 + (t >> 2)) * (long)K + (t & 3) * 8;
  const ushort* gB = Bw + (col0 + (t >> 2)) * (long)K + (t & 3) * 8;
  const int lo = wv * 512;
  const long K64 = 64l * K;

  gload_lds16(gA,       &sm[0][lo]);
  gload_lds16(gA + K64, &sm[0][lo + 2048]);
  gload_lds16(gB,       &sm[0][4096 + lo]);
  gload_lds16(gB + K64, &sm[0][4096 + lo + 2048]);

  for (int kt = 0; kt < K; kt += 32) {
    const int cb = (kt >> 5) & 1;
    __syncthreads();
    if (kt + 32 < K) {
      ushort* nb = &sm[cb ^ 1][0];
      gload_lds16(gA + kt + 32,       nb + lo);
      gload_lds16(gA + kt + 32 + K64, nb + lo + 2048);
      gload_lds16(gB + kt + 32,       nb + 4096 + lo);
      gload_lds16(gB + kt + 32 + K64, nb + 4096 + lo + 2048);
    }
    const ushort* Asb = &sm[cb][0];
    const ushort* Bsb = &sm[cb][4096];
    bf16x8 af[4], bf[4];
#pragma unroll
    for (int mi = 0; mi < 4; mi++)
      af[mi] = *(const bf16x8*)&Asb[(wm + mi * 16 + ln) * 32 + qd * 8];
#pragma unroll
    for (int ni = 0; ni < 4; ni++)
      bf[ni] = *(const bf16x8*)&Bsb[(wn + ni * 16 + ln) * 32 + qd * 8];
#pragma unroll
    for (int mi = 0; mi < 4; mi++)
#pragma unroll
      for (int ni = 0; ni < 4; ni++)
        acc[mi][ni] = __builtin_amdgcn_mfma_f32_16x16x32_bf16(af[mi], bf[ni], acc[mi][ni], 0, 0, 0);
  }

  float bv[4];
#pragma unroll
  for (int ni = 0; ni < 4; ni++) bv[ni] = bias[col0 + wn + ni * 16 + ln];

#pragma unroll
  for (int mi = 0; mi < 4; mi++)
#pragma unroll
    for (int ni = 0; ni < 4; ni++)
#pragma unroll
      for (int r = 0; r < 4; r++) {
        long row = row0 + wm + mi * 16 + qd * 4 + r;
        long col = col0 + wn + ni * 16 + ln;
        Cout[row * ldc + col] = acc[mi][ni][r] + bv[ni];
      }
}

// ---------------------------------------------------------------- flash attention v8
// v7 + V DIRECT FROM GLOBAL (m169: drop LDS staging for L2-resident operands — vt is
// 4 MB total, 512 KB/kv-head, each 128 B V-row line consumed exactly once per tile).
// Removes the V DMA + 16 KB/wave/tile of LDS reads: LDS bytes per MFMA halved, LDS
// shrinks 64->34.8 KB -> 4 blocks/CU (16 waves, 2x TLP). V-frags prefetched per kb
// (8x16 B) before the QK MFMAs so L2 latency hides under QK+softmax.
// K staging unchanged (DMA dbuf + XOR-chunk global-side swizzle, conflict-free).
__global__ __launch_bounds__(256, 4) void flash_kernel(
    const ushort* __restrict__ qk, const ushort* __restrict__ vt,
    ushort* __restrict__ ctx)
{
  __shared__ ushort smem[17408];  // K buf0 @0, buf1 @8192 (each 64x128); epilogue Obuf[128][136]
  const int t = threadIdx.x, lane = t & 63, wv = t >> 6;
  const int h2 = lane >> 5, m = lane & 31;
  const int q0 = blockIdx.x * 128;
  const int b = blockIdx.y >> 4, h = blockIdx.y & 15;
  const long rb = (long)b * 2048;
  const ushort* Qg  = qk + (rb + q0) * 2560 + h * 128;
  const ushort* Kg  = qk + rb * 2560 + 2048 + (h >> 2) * 128;
  const ushort* Vtg = vt + ((long)(h >> 2) * 128) * 4096 + rb;

  // Q B-frags in registers: lane (h2, m) holds Q[q = wv*32+m][d = 16*s2 + 8*h2 + 0..7]
  bf16x8 qf[8];
  {
    const ushort* qrow = Qg + (long)(wv * 32 + m) * 2560 + h2 * 8;
#pragma unroll
    for (int s2 = 0; s2 < 8; s2++)
      qf[s2] = *(const bf16x8*)(qrow + s2 * 16);
  }

  f32x16 oacc[4];
#pragma unroll
  for (int d = 0; d < 4; d++)
#pragma unroll
    for (int r = 0; r < 16; r++) oacc[d][r] = 0.f;
  float l_run = 0.f;

  // K staging addresses (tile 0), XOR-chunk swizzle on global side
  const ushort* gK[4];
#pragma unroll
  for (int s = 0; s < 4; s++) {
    int krow = wv * 16 + s * 4 + (lane >> 4);              // 0..63
    int kcd  = (lane & 15) ^ (krow & 15);
    gK[s] = Kg + (long)krow * 2560 + kcd * 8;
  }
  const int ldsK = wv * 16 * 128;                          // + s*4*128

  // per-lane V base: row m (+db*32), chunk h2; col = kt + (4kb+2sh)*8
  const ushort* Vb = Vtg + (long)m * 4096 + h2 * 8;

  // preload K tile 0 -> buf 0, advance to tile 1
#pragma unroll
  for (int s = 0; s < 4; s++) gload_lds16(gK[s], smem + ldsK + s * 512);
#pragma unroll
  for (int s = 0; s < 4; s++) gK[s] += 64l * 2560;

  const int mk = (m & 15);    // K swizzle key

  for (int kt = 0; kt < 2048; kt += 64) {
    const int cb = (kt >> 6) & 1;
    __syncthreads();   // drains DMA for this tile; prev tile's LDS reads done
    if (kt < 1984) {   // issue K tile i+1 into the other buffer
      ushort* nb = smem + (cb ^ 1) * 8192;
#pragma unroll
      for (int s = 0; s < 4; s++) gload_lds16(gK[s], nb + ldsK + s * 512);
#pragma unroll
      for (int s = 0; s < 4; s++) gK[s] += 64l * 2560;
    }
    const ushort* KsB = smem + cb * 8192;

    float s_sum = 0.f;
#pragma unroll
    for (int kb = 0; kb < 2; kb++) {
      // prefetch V frags for this kb (s = 2kb, 2kb+1): issued before QK MFMAs,
      // consumed after softmax — L2 latency hides under ~150 cyc of compute.
      bf16x8 vpre[8];
#pragma unroll
      for (int sh = 0; sh < 2; sh++)
#pragma unroll
        for (int db = 0; db < 4; db++)
          vpre[sh * 4 + db] =
            *(const bf16x8*)(Vb + (long)db * 131072 + kt + (4 * kb + 2 * sh) * 8);

      f32x16 sacc;
#pragma unroll
      for (int r = 0; r < 16; r++) sacc[r] = 0.f;
      __builtin_amdgcn_s_setprio(1);
#pragma unroll
      for (int s2 = 0; s2 < 8; s2++) {
        bf16x8 kf = *(const bf16x8*)&KsB[(32 * kb + m) * 128 + ((s2 * 2 + h2) ^ mk) * 8];
        sacc = __builtin_amdgcn_mfma_f32_32x32x16_bf16(kf, qf[s2], sacc, 0, 0, 0);
      }
      __builtin_amdgcn_s_setprio(0);
#pragma unroll
      for (int sh = 0; sh < 2; sh++) {
        float e0 = EXP2(sacc[8 * sh + 0]);
        float e1 = EXP2(sacc[8 * sh + 1]);
        float e2 = EXP2(sacc[8 * sh + 2]);
        float e3 = EXP2(sacc[8 * sh + 3]);
        float e4 = EXP2(sacc[8 * sh + 4]);
        float e5 = EXP2(sacc[8 * sh + 5]);
        float e6 = EXP2(sacc[8 * sh + 6]);
        float e7 = EXP2(sacc[8 * sh + 7]);
        s_sum += ((e0 + e1) + (e2 + e3)) + ((e4 + e5) + (e6 + e7));
        unsigned u0 = cvtpk(e0, e1);
        unsigned u1 = cvtpk(e2, e3);
        unsigned u2 = cvtpk(e4, e5);
        unsigned u3 = cvtpk(e6, e7);
        auto r0 = __builtin_amdgcn_permlane32_swap(u0, u2, false, false);
        auto r1 = __builtin_amdgcn_permlane32_swap(u1, u3, false, false);
        u32x4 pu;
        pu.x = r0[0];
        pu.y = r1[0];
        pu.z = r0[1];
        pu.w = r1[1];
        bf16x8 pfv = __builtin_bit_cast(bf16x8, pu);
        __builtin_amdgcn_s_setprio(1);
#pragma unroll
        for (int db = 0; db < 4; db++)
          oacc[db] = __builtin_amdgcn_mfma_f32_32x32x16_bf16(vpre[sh * 4 + db], pfv, oacc[db], 0, 0, 0);
        __builtin_amdgcn_s_setprio(0);
      }
    }
    l_run += s_sum + __int_as_float(__shfl_xor(__float_as_int(s_sum), 32, 64));
  }

  // epilogue: O^T/l -> LDS transpose -> coalesced ctx stores
  const float linv = 1.f / (l_run + 1e-10f);
  __syncthreads();                          // all waves done with K buffers
  ushort* Obuf = smem;                      // [128 q][136]
#pragma unroll
  for (int db = 0; db < 4; db++)
#pragma unroll
    for (int r = 0; r < 16; r++) {
      int d = db * 32 + (r & 3) + 8 * (r >> 2) + 4 * h2;
      Obuf[(wv * 32 + m) * 136 + d] = f2bf(oacc[db][r] * linv);
    }
  __syncthreads();
  {
    int qr = t >> 1;
    ushort* dst = ctx + (rb + q0 + qr) * 2048 + h * 128;
#pragma unroll
    for (int c = 0; c < 8; c++) {
      int off = ((t & 1) * 8 + c) * 8;
      *(uint4*)(dst + off) = *(const uint4*)&Obuf[qr * 136 + off];
    }
  }
}

// ---------------------------------------------------------------- launch
extern "C" void kernel_launch(void* const* d_in, const int* in_sizes, int n_in,
                              void* d_out, int out_size, void* d_ws, size_t ws_size,
                              hipStream_t stream)
{
  const float* hs = (const float*)d_in[0];
  const float* qw = (const float*)d_in[1];
  const float* qb = (const float*)d_in[2];
  const float* kw = (const float*)d_in[3];
  const float* kb = (const float*)d_in[4];
  const float* vw = (const float*)d_in[5];
  const float* vb = (const float*)d_in[6];
  const float* ow = (const float*)d_in[7];
  const float* ob = (const float*)d_in[8];

  char* ws = (char*)d_ws;
  ushort* hs_b   = (ushort*)(ws);                 // 16,777,216 B
  ushort* qkvw_b = (ushort*)(ws + 16777216);      // 12,582,912 B
  ushort* ow_b   = (ushort*)(ws + 29360128);      //  8,388,608 B
  float*  qkvb   = (float*) (ws + 37748736);      //     12,288 B
  ushort* qkbuf  = (ushort*)(ws + 37761024);      // 20,971,520 B  [4096][2560]
  ushort* vtbuf  = (ushort*)(ws + 58732544);      //  4,194,304 B  [512][4096]
  ushort* ctx    = (ushort*)(ws + 62926848);      // 16,777,216 B
  // rope table lives at the head of ctx: only needed until gemm_qkv completes;
  // flash overwrites ctx afterwards (stream-ordered, safe). 2048*64*8 B = 1 MB.
  float2* rope_tab = (float2*)(ws + 62926848);

  prep_kernel<<<1024, 256, 0, stream>>>(hs, qw, kw, vw, ow, qb, kb, vb,
                                        hs_b, qkvw_b, ow_b, qkvb, rope_tab);
  gemm_qkv<<<dim3(32, 24), 256, 0, stream>>>(hs_b, qkvw_b, qkvb, qkbuf, vtbuf,
                                             rope_tab);
  flash_kernel<<<dim3(16, 32), 256, 0, stream>>>(qkbuf, vtbuf, ctx);
  gemm_bt<<<dim3(32, 16), 256, 0, stream>>>(ctx, ow_b, ob, (float*)d_out,
                                            2048, 2048);
}

// Round 7
// 304.295 us; speedup vs baseline: 2.3679x; 2.3679x over previous
//
#include <hip/hip_runtime.h>
#include <hip/hip_bf16.h>
#include <math.h>

typedef __attribute__((ext_vector_type(8))) short bf16x8;
typedef __attribute__((ext_vector_type(4))) float f32x4;
typedef __attribute__((ext_vector_type(16))) float f32x16;
typedef __attribute__((ext_vector_type(4))) unsigned int u32x4;

#if __has_builtin(__builtin_amdgcn_exp2f)
#define EXP2(x) __builtin_amdgcn_exp2f(x)
#else
#define EXP2(x) __expf((x) * 0.6931471805599453f)
#endif

__device__ __forceinline__ ushort f2bf(float f) {
  unsigned u = __float_as_uint(f);
  u = u + 0x7FFFu + ((u >> 16) & 1u);
  return (ushort)(u >> 16);
}
__device__ __forceinline__ float bf2f(ushort h) {
  return __uint_as_float(((unsigned)h) << 16);
}
// single-instruction packed f32->bf16 pair (RNE, same as manual round)
__device__ __forceinline__ unsigned cvtpk(float a, float b) {
  unsigned r;
  asm("v_cvt_pk_bf16_f32 %0, %1, %2" : "=v"(r) : "v"(a), "v"(b));
  return r;
}
__device__ __forceinline__ void gload_lds16(const ushort* g, ushort* l) {
  __builtin_amdgcn_global_load_lds((const __attribute__((address_space(1))) void*)g,
                                   (__attribute__((address_space(3))) void*)l, 16, 0, 0);
}

// ---------------------------------------------------------------- prep: casts + packing + rope table
__global__ __launch_bounds__(256) void prep_kernel(
    const float* __restrict__ hs, const float* __restrict__ qw,
    const float* __restrict__ kw, const float* __restrict__ vw,
    const float* __restrict__ ow, const float* __restrict__ qb,
    const float* __restrict__ kb, const float* __restrict__ vb,
    ushort* __restrict__ hs_b, ushort* __restrict__ qkvw_b,
    ushort* __restrict__ ow_b, float* __restrict__ qkvb,
    float2* __restrict__ rope_tab)
{
  const int idx = blockIdx.x * 256 + threadIdx.x;
  const int stride = gridDim.x * 256;
  const float4* hs4 = (const float4*)hs;
  const float4* qw4 = (const float4*)qw;
  const float4* kw4 = (const float4*)kw;
  const float4* vw4 = (const float4*)vw;
  const float4* ow4 = (const float4*)ow;
  ushort4* hsb4 = (ushort4*)hs_b;
  ushort4* qkvwb4 = (ushort4*)qkvw_b;
  ushort4* owb4 = (ushort4*)ow_b;

  for (int i = idx; i < 2097152; i += stride) {
    float4 v = hs4[i];
    ushort4 o; o.x=f2bf(v.x); o.y=f2bf(v.y); o.z=f2bf(v.z); o.w=f2bf(v.w);
    hsb4[i] = o;
  }
  for (int i = idx; i < 1048576; i += stride) {
    float4 v = qw4[i];
    ushort4 o; o.x=f2bf(v.x); o.y=f2bf(v.y); o.z=f2bf(v.z); o.w=f2bf(v.w);
    qkvwb4[i] = o;
  }
  for (int i = idx; i < 262144; i += stride) {
    float4 v = kw4[i];
    ushort4 o; o.x=f2bf(v.x); o.y=f2bf(v.y); o.z=f2bf(v.z); o.w=f2bf(v.w);
    qkvwb4[1048576 + i] = o;
  }
  for (int i = idx; i < 262144; i += stride) {
    float4 v = vw4[i];
    ushort4 o; o.x=f2bf(v.x); o.y=f2bf(v.y); o.z=f2bf(v.z); o.w=f2bf(v.w);
    qkvwb4[1310720 + i] = o;
  }
  for (int i = idx; i < 1048576; i += stride) {
    float4 v = ow4[i];
    ushort4 o; o.x=f2bf(v.x); o.y=f2bf(v.y); o.z=f2bf(v.z); o.w=f2bf(v.w);
    owb4[i] = o;
  }
  for (int i = idx; i < 3072; i += stride)
    qkvb[i] = (i < 2048) ? qb[i] : (i < 2560 ? kb[i - 2048] : vb[i - 2560]);
  // rope cos/sin table: [pos 0..2047][pair 0..63]
  for (int i = idx; i < 131072; i += stride) {
    int pos = i >> 6, d = i & 63;
    float inv = __expf((float)d * -0.14391156831212787f);
    float ang = (float)pos * inv;
    rope_tab[i] = make_float2(cosf(ang), sinf(ang));
  }
}

// ---------------------------------------------------------------- 128x128 GEMM, 2 waves of 64x128
// Per-wave geometry from R5's gemm256 (measured ~860 TF-equiv per busy CU): 12
// ds_read_b128 per 32 MFMAs (0.375 vs 0.5 for 64x64 waves) lifts the LDS-BW cap.
// 128-thread blocks -> grids 768/512 = exact multiples of 256 CUs (R5's only flaw
// was 192-block underfill). Counted-vmcnt 2-phase schedule (T3+T4), gates derived:
// 8 loads/tile; p0 issues 4 A-loads then vmcnt(4) = drain this tile's 8, keep 4 in
// flight; p1 issues 4 B-loads; vmcnt(0) only on the last tile. End-of-tile barrier
// frees the slot the next tile's DMA re-targets. asm fences stop ds hoist (rule #18).
// MODE 1: QKV + fused rope (R2's verified epilogue: all 8 frag-cols in-wave, pair
// (d,d+64) = (ni, ni+4)), V-transpose store. MODE 0: f32 out, ldc=2048.
template<int MODE>
__global__ __launch_bounds__(128, 2) void gemm128(
    const ushort* __restrict__ A, const ushort* __restrict__ Bw,
    const float* __restrict__ bias, void* __restrict__ out,
    ushort* __restrict__ vt, const float2* __restrict__ tab)
{
  __shared__ ushort smem[2][8192];  // slot: A[128][32] @0, B[128][32] @4096
  const int tid = threadIdx.x;               // 0..127
  const int lane = tid & 63, wv = tid >> 6;  // 2 waves
  const int qd = lane >> 4, ln = lane & 15;
  const long row0 = (long)blockIdx.x * 128, col0 = (long)blockIdx.y * 128;

  f32x4 acc[4][8];   // mi: 4 row-frags (64 rows of this wave), ni: 8 col-frags
#pragma unroll
  for (int i = 0; i < 4; i++)
#pragma unroll
    for (int j = 0; j < 8; j++) acc[i][j] = (f32x4){0.f, 0.f, 0.f, 0.f};

  const ushort* gA = A + (row0 + (tid >> 2)) * 2048l + (tid & 3) * 8;
  const ushort* gB = Bw + (col0 + (tid >> 2)) * 2048l + (tid & 3) * 8;
  const long R32 = 32l * 2048;     // +32 rows
  const int tid8 = tid * 8;        // = row*32 + chunk*8 within a 32-row band

  // prologue: stage tile 0 -> slot 0 (A bands 0..3, B bands 0..3)
#pragma unroll
  for (int i = 0; i < 4; i++) gload_lds16(gA + i * R32, &smem[0][i * 1024 + tid8]);
#pragma unroll
  for (int i = 0; i < 4; i++) gload_lds16(gB + i * R32, &smem[0][4096 + i * 1024 + tid8]);

  for (int kt = 0; kt < 2048; kt += 32) {
    const int st = (kt >> 5) & 1;
    const ushort* As = smem[st];
    const ushort* Bs = As + 4096;
    ushort* Dst = smem[st ^ 1];
    const bool more = (kt + 32) < 2048;

    // ---- phase 0: issue A(next), counted gate, rows wv*64+0..31 ----
    if (more) {
#pragma unroll
      for (int i = 0; i < 4; i++)
        gload_lds16(gA + kt + 32 + i * R32, Dst + i * 1024 + tid8);
      asm volatile("s_waitcnt vmcnt(4)" ::: "memory");  // drain tile-kt's 8 loads
    } else {
      asm volatile("s_waitcnt vmcnt(0)" ::: "memory");
    }
    __builtin_amdgcn_s_barrier();
    asm volatile("" ::: "memory");
    bf16x8 bf[8], af[2];
#pragma unroll
    for (int ni = 0; ni < 8; ni++)
      bf[ni] = *(const bf16x8*)&Bs[(ni * 16 + ln) * 32 + qd * 8];
#pragma unroll
    for (int mi = 0; mi < 2; mi++)
      af[mi] = *(const bf16x8*)&As[(wv * 64 + mi * 16 + ln) * 32 + qd * 8];
    __builtin_amdgcn_s_setprio(1);
#pragma unroll
    for (int mi = 0; mi < 2; mi++)
#pragma unroll
      for (int ni = 0; ni < 8; ni++)
        acc[mi][ni] = __builtin_amdgcn_mfma_f32_16x16x32_bf16(af[mi], bf[ni], acc[mi][ni], 0, 0, 0);
    __builtin_amdgcn_s_setprio(0);

    // ---- phase 1: rows wv*64+32..63, issue B(next) ----
    bf16x8 ag[2];
#pragma unroll
    for (int mi = 0; mi < 2; mi++)
      ag[mi] = *(const bf16x8*)&As[(wv * 64 + 32 + mi * 16 + ln) * 32 + qd * 8];
    if (more) {
#pragma unroll
      for (int i = 0; i < 4; i++)
        gload_lds16(gB + kt + 32 + i * R32, Dst + 4096 + i * 1024 + tid8);
    }
    __builtin_amdgcn_s_setprio(1);
#pragma unroll
    for (int mi = 0; mi < 2; mi++)
#pragma unroll
      for (int ni = 0; ni < 8; ni++)
        acc[mi + 2][ni] = __builtin_amdgcn_mfma_f32_16x16x32_bf16(ag[mi], bf[ni], acc[mi + 2][ni], 0, 0, 0);
    __builtin_amdgcn_s_setprio(0);
    asm volatile("" ::: "memory");   // pin ds_reads above the barrier
    __builtin_amdgcn_s_barrier();
    asm volatile("" ::: "memory");
  }

  float bv[8];
#pragma unroll
  for (int ni = 0; ni < 8; ni++) bv[ni] = bias[col0 + ni * 16 + ln];

  if (MODE == 0) {
    float* C = (float*)out;
#pragma unroll
    for (int mi = 0; mi < 4; mi++)
#pragma unroll
      for (int ni = 0; ni < 8; ni++)
#pragma unroll
        for (int r = 0; r < 4; r++) {
          long row = row0 + wv * 64 + mi * 16 + qd * 4 + r;
          long col = col0 + ni * 16 + ln;
          C[row * 2048 + col] = acc[mi][ni][r] + bv[ni];
        }
  } else if (col0 >= 2560) {
    // V: transposed store into vt [512][4096]
#pragma unroll
    for (int mi = 0; mi < 4; mi++)
#pragma unroll
      for (int ni = 0; ni < 8; ni++)
#pragma unroll
        for (int r = 0; r < 4; r++) {
          long row = row0 + wv * 64 + mi * 16 + qd * 4 + r;
          long col = col0 + ni * 16 + ln - 2560;
          vt[col * 4096 + row] = f2bf(acc[mi][ni][r] + bv[ni]);
        }
  } else {
    // Q or K: fused rope (R2-verified): pair (d, d+64) = (ni, ni+4), in-lane.
    ushort* qkbuf = (ushort*)out;
    const float sc = (col0 < 2048) ? 0.12751744399764505f : 1.0f;  // log2(e)/sqrt(128)
#pragma unroll
    for (int mi = 0; mi < 4; mi++)
#pragma unroll
      for (int ni = 0; ni < 4; ni++) {
        const int d = ni * 16 + ln;           // 0..63
#pragma unroll
        for (int r = 0; r < 4; r++) {
          long row = row0 + wv * 64 + mi * 16 + qd * 4 + r;
          int pos = (int)(row & 2047);
          float2 cs = tab[pos * 64 + d];
          float c = cs.x * sc, s = cs.y * sc;
          float v0 = acc[mi][ni][r]     + bv[ni];
          float v1 = acc[mi][ni + 4][r] + bv[ni + 4];
          ushort* p = qkbuf + row * 2560 + col0 + d;
          p[0]  = f2bf(v0 * c - v1 * s);
          p[64] = f2bf(v1 * c + v0 * s);
        }
      }
  }
}

// ---------------------------------------------------------------- flash attention v7 (proven: 82 µs)
// T12 softmax (exp2 with log2e folded in rope scale, v_cvt_pk_bf16_f32, permlane32_swap),
// T5 setprio around MFMA clusters, DMA double-buffer, XOR-chunk swizzle on global side.
// LDS-staged V (v8's V-in-reg spilled: 128-VGPR cap at occ 4 vs ~180 needed).
__global__ __launch_bounds__(256, 2) void flash_kernel(
    const ushort* __restrict__ qk, const ushort* __restrict__ vt,
    ushort* __restrict__ ctx)
{
  __shared__ ushort smem[32768];  // buf0: Ks[64][128]@0, Vts[128][64]@8192; buf1 @16384
  const int t = threadIdx.x, lane = t & 63, wv = t >> 6;
  const int h2 = lane >> 5, m = lane & 31;
  const int q0 = blockIdx.x * 128;
  const int b = blockIdx.y >> 4, h = blockIdx.y & 15;
  const long rb = (long)b * 2048;
  const ushort* Qg  = qk + (rb + q0) * 2560 + h * 128;
  const ushort* Kg  = qk + rb * 2560 + 2048 + (h >> 2) * 128;
  const ushort* Vtg = vt + ((long)(h >> 2) * 128) * 4096 + rb;

  // Q B-frags in registers: lane (h2, m) holds Q[q = wv*32+m][d = 16*s2 + 8*h2 + 0..7]
  bf16x8 qf[8];
  {
    const ushort* qrow = Qg + (long)(wv * 32 + m) * 2560 + h2 * 8;
#pragma unroll
    for (int s2 = 0; s2 < 8; s2++)
      qf[s2] = *(const bf16x8*)(qrow + s2 * 16);
  }

  f32x16 oacc[4];
#pragma unroll
  for (int d = 0; d < 4; d++)
#pragma unroll
    for (int r = 0; r < 16; r++) oacc[d][r] = 0.f;
  float l_run = 0.f;

  // per-lane global staging addresses (tile 0), swizzled chunk on global side
  const ushort* gK[4];
  const ushort* gV[4];
#pragma unroll
  for (int s = 0; s < 4; s++) {
    int krow = wv * 16 + s * 4 + (lane >> 4);              // 0..63
    int kcd  = (lane & 15) ^ (krow & 15);
    gK[s] = Kg + (long)krow * 2560 + kcd * 8;
    int vrow = wv * 32 + s * 8 + (lane >> 3);              // 0..127
    int vcd  = (lane & 7) ^ ((lane >> 3) & 7);
    gV[s] = Vtg + (long)vrow * 4096 + vcd * 8;
  }
  const int ldsK = wv * 16 * 128;                          // + s*4*128
  const int ldsV = 8192 + wv * 32 * 64;                    // + s*8*64

  // preload tile 0 -> buf 0, advance pointers to tile 1
#pragma unroll
  for (int s = 0; s < 4; s++) gload_lds16(gK[s], smem + ldsK + s * 512);
#pragma unroll
  for (int s = 0; s < 4; s++) gload_lds16(gV[s], smem + ldsV + s * 512);
#pragma unroll
  for (int s = 0; s < 4; s++) { gK[s] += 64l * 2560; gV[s] += 64; }

  const int mk = (m & 15);    // K swizzle key
  const int mv = (m & 7);     // V swizzle key

  for (int kt = 0; kt < 2048; kt += 64) {
    const int cb = (kt >> 6) & 1;
    __syncthreads();   // drains DMA for this tile; prev tile's LDS reads done
    if (kt < 1984) {   // issue tile i+1 into the other buffer (in flight across compute)
      ushort* nb = smem + (cb ^ 1) * 16384;
#pragma unroll
      for (int s = 0; s < 4; s++) gload_lds16(gK[s], nb + ldsK + s * 512);
#pragma unroll
      for (int s = 0; s < 4; s++) gload_lds16(gV[s], nb + ldsV + s * 512);
#pragma unroll
      for (int s = 0; s < 4; s++) { gK[s] += 64l * 2560; gV[s] += 64; }
    }
    const ushort* KsB  = smem + cb * 16384;
    const ushort* VtsB = KsB + 8192;

    float s_sum = 0.f;
#pragma unroll
    for (int kb = 0; kb < 2; kb++) {
      f32x16 sacc;
#pragma unroll
      for (int r = 0; r < 16; r++) sacc[r] = 0.f;
      __builtin_amdgcn_s_setprio(1);
#pragma unroll
      for (int s2 = 0; s2 < 8; s2++) {
        bf16x8 kf = *(const bf16x8*)&KsB[(32 * kb + m) * 128 + ((s2 * 2 + h2) ^ mk) * 8];
        sacc = __builtin_amdgcn_mfma_f32_32x32x16_bf16(kf, qf[s2], sacc, 0, 0, 0);
      }
      __builtin_amdgcn_s_setprio(0);
#pragma unroll
      for (int sh = 0; sh < 2; sh++) {
        float e0 = EXP2(sacc[8 * sh + 0]);
        float e1 = EXP2(sacc[8 * sh + 1]);
        float e2 = EXP2(sacc[8 * sh + 2]);
        float e3 = EXP2(sacc[8 * sh + 3]);
        float e4 = EXP2(sacc[8 * sh + 4]);
        float e5 = EXP2(sacc[8 * sh + 5]);
        float e6 = EXP2(sacc[8 * sh + 6]);
        float e7 = EXP2(sacc[8 * sh + 7]);
        s_sum += ((e0 + e1) + (e2 + e3)) + ((e4 + e5) + (e6 + e7));
        unsigned u0 = cvtpk(e0, e1);
        unsigned u1 = cvtpk(e2, e3);
        unsigned u2 = cvtpk(e4, e5);
        unsigned u3 = cvtpk(e6, e7);
        auto r0 = __builtin_amdgcn_permlane32_swap(u0, u2, false, false);
        auto r1 = __builtin_amdgcn_permlane32_swap(u1, u3, false, false);
        u32x4 pu;
        pu.x = r0[0];
        pu.y = r1[0];
        pu.z = r0[1];
        pu.w = r1[1];
        bf16x8 pfv = __builtin_bit_cast(bf16x8, pu);
        const int s = 2 * kb + sh;
        __builtin_amdgcn_s_setprio(1);
#pragma unroll
        for (int db = 0; db < 4; db++) {
          bf16x8 vf = *(const bf16x8*)&VtsB[(db * 32 + m) * 64 + ((s * 2 + h2) ^ mv) * 8];
          oacc[db] = __builtin_amdgcn_mfma_f32_32x32x16_bf16(vf, pfv, oacc[db], 0, 0, 0);
        }
        __builtin_amdgcn_s_setprio(0);
      }
    }
    l_run += s_sum + __int_as_float(__shfl_xor(__float_as_int(s_sum), 32, 64));
  }

  // epilogue: O^T/l -> LDS transpose -> coalesced ctx stores
  const float linv = 1.f / (l_run + 1e-10f);
  __syncthreads();                          // all waves done with staging buffers
  ushort* Obuf = smem;                      // [128 q][136]
#pragma unroll
  for (int db = 0; db < 4; db++)
#pragma unroll
    for (int r = 0; r < 16; r++) {
      int d = db * 32 + (r & 3) + 8 * (r >> 2) + 4 * h2;
      Obuf[(wv * 32 + m) * 136 + d] = f2bf(oacc[db][r] * linv);
    }
  __syncthreads();
  {
    int qr = t >> 1;
    ushort* dst = ctx + (rb + q0 + qr) * 2048 + h * 128;
#pragma unroll
    for (int c = 0; c < 8; c++) {
      int off = ((t & 1) * 8 + c) * 8;
      *(uint4*)(dst + off) = *(const uint4*)&Obuf[qr * 136 + off];
    }
  }
}

// ---------------------------------------------------------------- launch
extern "C" void kernel_launch(void* const* d_in, const int* in_sizes, int n_in,
                              void* d_out, int out_size, void* d_ws, size_t ws_size,
                              hipStream_t stream)
{
  const float* hs = (const float*)d_in[0];
  const float* qw = (const float*)d_in[1];
  const float* qb = (const float*)d_in[2];
  const float* kw = (const float*)d_in[3];
  const float* kb = (const float*)d_in[4];
  const float* vw = (const float*)d_in[5];
  const float* vb = (const float*)d_in[6];
  const float* ow = (const float*)d_in[7];
  const float* ob = (const float*)d_in[8];

  char* ws = (char*)d_ws;
  ushort* hs_b   = (ushort*)(ws);                 // 16,777,216 B
  ushort* qkvw_b = (ushort*)(ws + 16777216);      // 12,582,912 B
  ushort* ow_b   = (ushort*)(ws + 29360128);      //  8,388,608 B
  float*  qkvb   = (float*) (ws + 37748736);      //     12,288 B
  ushort* qkbuf  = (ushort*)(ws + 37761024);      // 20,971,520 B  [4096][2560]
  ushort* vtbuf  = (ushort*)(ws + 58732544);      //  4,194,304 B  [512][4096]
  ushort* ctx    = (ushort*)(ws + 62926848);      // 16,777,216 B
  // rope table lives at the head of ctx: only needed until gemm_qkv completes;
  // flash overwrites ctx afterwards (stream-ordered, safe). 2048*64*8 B = 1 MB.
  float2* rope_tab = (float2*)(ws + 62926848);

  prep_kernel<<<1024, 256, 0, stream>>>(hs, qw, kw, vw, ow, qb, kb, vb,
                                        hs_b, qkvw_b, ow_b, qkvb, rope_tab);
  gemm128<1><<<dim3(32, 24), 128, 0, stream>>>(hs_b, qkvw_b, qkvb, (void*)qkbuf,
                                               vtbuf, rope_tab);
  flash_kernel<<<dim3(16, 32), 256, 0, stream>>>(qkbuf, vtbuf, ctx);
  gemm128<0><<<dim3(32, 16), 128, 0, stream>>>(ctx, ow_b, ob, d_out,
                                               nullptr, nullptr);
}